// Round 3
// baseline (377.226 us; speedup 1.0000x reference)
//
#include <hip/hip_runtime.h>

#define N    8192
#define DT   768
#define DO   512
#define BM   128
#define BN   128
#define TI   (N / BM)   // 64
#define TJ   (N / BN)   // 64
#define NTILE (TI * (TI + 1) / 2)   // 2080 upper-triangle tiles (2080 % 8 == 0)
#define NSLOT (2 * TJ)              // 128 partial slots per row
#define PL    ((size_t)NSLOT * N)   // one SoA plane: 128*8192 floats = 4 MB
#define NKT   (DT / 32)             // 24 teacher K-steps
#define NKO   (DO / 32)             // 16 student K-steps

typedef __attribute__((ext_vector_type(8))) short   short8;   // 8 bf16 = 4 VGPRs
typedef __attribute__((ext_vector_type(4))) float   floatx4;

struct alignas(8) us4 { unsigned short x[4]; };

// round-to-nearest-even fp32 -> bf16
__device__ inline unsigned short f2bf(float x) {
    union { float f; unsigned int u; } v; v.f = x;
    unsigned int r = v.u + 0x7fffu + ((v.u >> 16) & 1u);
    return (unsigned short)(r >> 16);
}
__device__ inline float bf2f(unsigned short u) {
    union { unsigned int u; float f; } v; v.u = ((unsigned int)u) << 16;
    return v.f;
}

// async global->LDS, 16B per lane (global_load_lds_dwordx4)
__device__ inline void gl2lds16(const unsigned short* g, unsigned short* l) {
    __builtin_amdgcn_global_load_lds(
        (const __attribute__((address_space(1))) unsigned int*)(const void*)g,
        (__attribute__((address_space(3))) unsigned int*)(void*)l,
        16, 0, 0);
}

// stage one 128x32 A-tile and B-tile (bf16) into an LDS buffer.
// LDS destination LINEAR (global_load_lds writes base+lane*16); bank-conflict
// swizzle applied by permuting the GLOBAL source column chunk; matching XOR
// on the ds_read side (2-way residual = free).
template <int D>
__device__ inline void stage_tile(const unsigned short* __restrict__ Xi,
                                  const unsigned short* __restrict__ Xj,
                                  unsigned short* sAb, unsigned short* sBb,
                                  int i0, int j0, int k, int t) {
    #pragma unroll
    for (int h = 0; h < 2; ++h) {
        const int idx = t + h * 256;        // 0..511; lane-contiguous per wave
        const int r   = idx >> 2;
        const int cs  = ((idx & 3) ^ ((r >> 1) & 3)) << 3;   // swizzled col-chunk
        gl2lds16(Xi + (size_t)(i0 + r) * D + k + cs, &sAb[idx * 8]);
        gl2lds16(Xj + (size_t)(j0 + r) * D + k + cs, &sBb[idx * 8]);
    }
}

// fragment loads + 16 MFMA for one 32-wide K-step
__device__ inline void mfma_step(const unsigned short* __restrict__ sAb,
                                 const unsigned short* __restrict__ sBb,
                                 floatx4 (&acc)[4][4],
                                 int wm, int wn, int lr, int lgx) {
    short8 af[4], bf[4];
    #pragma unroll
    for (int mi = 0; mi < 4; ++mi)
        af[mi] = *(const short8*)&sAb[(wm * 64 + mi * 16 + lr) * 32 + (lgx << 3)];
    #pragma unroll
    for (int ni = 0; ni < 4; ++ni)
        bf[ni] = *(const short8*)&sBb[(wn * 64 + ni * 16 + lr) * 32 + (lgx << 3)];
    #pragma unroll
    for (int mi = 0; mi < 4; ++mi)
        #pragma unroll
        for (int ni = 0; ni < 4; ++ni)
            acc[mi][ni] = __builtin_amdgcn_mfma_f32_16x16x32_bf16(
                af[mi], bf[ni], acc[mi][ni], 0, 0, 0);
}

// drain prefetch loads + workgroup barrier (raw: do NOT use __syncthreads(),
// it would emit vmcnt(0) at the WRONG place and serialize the pipeline)
__device__ inline void drain_barrier() {
    asm volatile("s_waitcnt vmcnt(0)" ::: "memory");
    __builtin_amdgcn_s_barrier();
    asm volatile("" ::: "memory");
}

// ---------------- row-normalize fp32 -> bf16 (one wave per row) ----------------
__global__ void norm_kernel(const float* __restrict__ Tg,
                            const float* __restrict__ Mo,
                            unsigned short* __restrict__ Xt,
                            unsigned short* __restrict__ Xo,
                            float* __restrict__ zero_me) {
    if (blockIdx.x == 0 && threadIdx.x == 0) zero_me[0] = 0.0f;
    int bid = blockIdx.x;
    const float* X; unsigned short* Xn; int D;
    if (bid < N / 4) { X = Tg; Xn = Xt; D = DT; }
    else             { bid -= N / 4; X = Mo; Xn = Xo; D = DO; }
    const int row  = bid * 4 + (threadIdx.x >> 6);
    const int lane = threadIdx.x & 63;
    const float* xr = X + (size_t)row * D;
    float ss = 0.0f;
    for (int c = lane * 4; c < D; c += 256) {
        const floatx4 v = *(const floatx4*)(xr + c);
        ss += v[0] * v[0] + v[1] * v[1] + v[2] * v[2] + v[3] * v[3];
    }
    #pragma unroll
    for (int m = 32; m >= 1; m >>= 1) ss += __shfl_xor(ss, m);
    const float scale = 1.0f / fmaxf(sqrtf(ss), 1e-8f);
    unsigned short* outr = Xn + (size_t)row * D;
    for (int c = lane * 4; c < D; c += 256) {
        const floatx4 v = *(const floatx4*)(xr + c);
        us4 o;
        #pragma unroll
        for (int j = 0; j < 4; ++j) o.x[j] = f2bf(v[j] * scale);
        *(us4*)(outr + c) = o;
    }
}

// ---------------- fused dual-GEMM + softmax-stat tile kernel ----------------
// Symmetric-tile scheme (ti <= tj, row-sums + col-sums) as R1/R2.
// NEW in R3: 2-phase pipelined K-loop (double-buffered LDS, prefetch next
// K-step before computing current, single raw barrier per step, vmcnt(0)
// only after compute). Teacher's last step prefetches the student's k=0 tile;
// teacher epilogue runs with the student pipeline already primed.
// W = e3 parked in 32 packed VGPRs (per-thread private; was 32 KB of LDS).
__launch_bounds__(256, 3)
__global__ void fused_kernel(const unsigned short* __restrict__ Xt,
                             const unsigned short* __restrict__ Xo,
                             float* __restrict__ partials) {
    __shared__ unsigned short sA[2][BM * 32];     // 2 x 8 KB
    __shared__ unsigned short sB[2][BN * 32];     // 2 x 8 KB   (total 32 KB)

    const int t    = threadIdx.x;
    const int lane = t & 63;
    const int w    = t >> 6;
    const int wm   = w >> 1, wn = w & 1;
    const int lr   = lane & 15, lg = lane >> 4;
    const int lgx  = lg ^ ((lr >> 1) & 3);        // swizzled read chunk index

    // Bijective chunked XCD swizzle (NTILE % 8 == 0 -> exact): XCD k owns a
    // contiguous range of the triangle enumeration -> A-panel L2-resident.
    const int swb = (blockIdx.x & 7) * (NTILE / 8) + (blockIdx.x >> 3);
    int rem = swb, ti = 0;
    while (rem >= TI - ti) { rem -= TI - ti; ++ti; }
    const int tj = ti + rem;
    const bool offdiag = (ti != tj);
    const int i0 = ti * BM, j0 = tj * BN;

    unsigned int w3p[32];                         // 64 bf16 teacher weights e3
    floatx4 acc[4][4];
    #pragma unroll
    for (int a = 0; a < 4; ++a)
        #pragma unroll
        for (int b = 0; b < 4; ++b)
            acc[a][b] = (floatx4){0.0f, 0.0f, 0.0f, 0.0f};

    // ---- prologue: stage teacher k=0 into buf0 and drain ----
    stage_tile<DT>(Xt, Xt, sA[0], sB[0], i0, j0, 0, t);
    drain_barrier();

    // ---- teacher K-loop (pipelined) ----
    for (int kt = 0; kt < NKT; ++kt) {
        const int cur = kt & 1, nxt = cur ^ 1;
        if (kt + 1 < NKT) stage_tile<DT>(Xt, Xt, sA[nxt], sB[nxt], i0, j0, (kt + 1) * 32, t);
        else              stage_tile<DO>(Xo, Xo, sA[nxt], sB[nxt], i0, j0, 0, t);
        mfma_step(sA[cur], sB[cur], acc, wm, wn, lr, lgx);
        drain_barrier();
    }
    // NKT=24 even -> student k=0 sits in buf0; student loop parity matches.

    // ---- teacher epilogue: Zt, V, Sum(e3*a) per row (both orientations);
    //      pack W=e3 into registers. C/D layout: col=lane&15, row=(lane>>4)*4+reg
    {
        float czt[4], cvv[4], cua[4];
        #pragma unroll
        for (int ni = 0; ni < 4; ++ni) { czt[ni] = 0.0f; cvv[ni] = 0.0f; cua[ni] = 0.0f; }
        #pragma unroll
        for (int mi = 0; mi < 4; ++mi) {
            #pragma unroll
            for (int r = 0; r < 4; ++r) {
                const int row = wm * 64 + mi * 16 + lg * 4 + r;
                const int gi  = i0 + row;
                float zt = 0.0f, vv = 0.0f, ua = 0.0f;
                #pragma unroll
                for (int ni = 0; ni < 4; ++ni) {
                    const int gj = j0 + wn * 64 + ni * 16 + lr;
                    const float a = acc[mi][ni][r];
                    float ea = __expf(a - 1.0f);
                    if (gi == gj) ea = 0.0f;               // diagonal -> prob 0
                    const float e3 = ea * ea * ea;
                    zt += ea; vv += e3; ua += e3 * a;
                    czt[ni] += ea; cvv[ni] += e3; cua[ni] += e3 * a;
                    const int idx = mi * 16 + ni * 4 + r;  // compile-time constant
                    const unsigned short h = f2bf(e3);
                    if (idx & 1) w3p[idx >> 1] |= ((unsigned int)h) << 16;
                    else         w3p[idx >> 1]  = (unsigned int)h;
                }
                #pragma unroll
                for (int m = 8; m >= 1; m >>= 1) {
                    zt += __shfl_xor(zt, m);
                    vv += __shfl_xor(vv, m);
                    ua += __shfl_xor(ua, m);
                }
                if (lr == 0) {
                    const size_t base = (size_t)(tj * 2 + wn) * N + gi;
                    partials[0 * PL + base] = zt;
                    partials[1 * PL + base] = vv;
                    partials[2 * PL + base] = ua;
                }
            }
        }
        if (offdiag) {
            #pragma unroll
            for (int ni = 0; ni < 4; ++ni) {
                #pragma unroll
                for (int m = 16; m <= 32; m <<= 1) {
                    czt[ni] += __shfl_xor(czt[ni], m);
                    cvv[ni] += __shfl_xor(cvv[ni], m);
                    cua[ni] += __shfl_xor(cua[ni], m);
                }
            }
            if (lg == 0) {
                #pragma unroll
                for (int ni = 0; ni < 4; ++ni) {
                    const int gj = j0 + wn * 64 + ni * 16 + lr;   // contiguous in lr
                    const size_t base = (size_t)(ti * 2 + wm) * N + gj;
                    partials[0 * PL + base] = czt[ni];
                    partials[1 * PL + base] = cvv[ni];
                    partials[2 * PL + base] = cua[ni];
                }
            }
        }
    }

    // ---- student K-loop (pipelined; k=0 already staged & drained) ----
    #pragma unroll
    for (int a = 0; a < 4; ++a)
        #pragma unroll
        for (int b = 0; b < 4; ++b)
            acc[a][b] = (floatx4){0.0f, 0.0f, 0.0f, 0.0f};

    for (int ko = 0; ko < NKO; ++ko) {
        const int cur = ko & 1, nxt = cur ^ 1;
        if (ko + 1 < NKO) stage_tile<DO>(Xo, Xo, sA[nxt], sB[nxt], i0, j0, (ko + 1) * 32, t);
        mfma_step(sA[cur], sB[cur], acc, wm, wn, lr, lgx);
        if (ko + 1 < NKO) drain_barrier();     // last step: nothing left to sync
    }

    // ---- student epilogue: Zo, Sum(W*b) per row (both orientations) ----
    {
        float czo[4], cwb[4];
        #pragma unroll
        for (int ni = 0; ni < 4; ++ni) { czo[ni] = 0.0f; cwb[ni] = 0.0f; }
        #pragma unroll
        for (int mi = 0; mi < 4; ++mi) {
            #pragma unroll
            for (int r = 0; r < 4; ++r) {
                const int row = wm * 64 + mi * 16 + lg * 4 + r;
                const int gi  = i0 + row;
                float zo = 0.0f, wb = 0.0f;
                #pragma unroll
                for (int ni = 0; ni < 4; ++ni) {
                    const int gj = j0 + wn * 64 + ni * 16 + lr;
                    const float b = acc[mi][ni][r];
                    float eb = __expf(b - 1.0f);
                    if (gi == gj) eb = 0.0f;
                    const int idx = mi * 16 + ni * 4 + r;  // compile-time constant
                    const unsigned int pw = w3p[idx >> 1];
                    const float wgt = bf2f((unsigned short)((idx & 1) ? (pw >> 16)
                                                                      : (pw & 0xffffu)));
                    zo += eb; wb += wgt * b;   // diag: W==0 -> no contribution
                    czo[ni] += eb; cwb[ni] += wgt * b;
                }
                #pragma unroll
                for (int m = 8; m >= 1; m >>= 1) {
                    zo += __shfl_xor(zo, m);
                    wb += __shfl_xor(wb, m);
                }
                if (lr == 0) {
                    const size_t base = (size_t)(tj * 2 + wn) * N + gi;
                    partials[3 * PL + base] = zo;
                    partials[4 * PL + base] = wb;
                }
            }
        }
        if (offdiag) {
            #pragma unroll
            for (int ni = 0; ni < 4; ++ni) {
                #pragma unroll
                for (int m = 16; m <= 32; m <<= 1) {
                    czo[ni] += __shfl_xor(czo[ni], m);
                    cwb[ni] += __shfl_xor(cwb[ni], m);
                }
            }
            if (lg == 0) {
                #pragma unroll
                for (int ni = 0; ni < 4; ++ni) {
                    const int gj = j0 + wn * 64 + ni * 16 + lr;   // contiguous in lr
                    const size_t base = (size_t)(ti * 2 + wm) * N + gj;
                    partials[3 * PL + base] = czo[ni];
                    partials[4 * PL + base] = cwb[ni];
                }
            }
        }
    }
}

// ---------------- final per-row combine + scalar reduce ----------------
// 128 blocks; each block: 64 rows, 4 waves split the 128 slots (32 each),
// LDS combine, wave 0 computes per-row loss + block partial -> one atomic.
__global__ void reduce_kernel(const float* __restrict__ partials,
                              float* __restrict__ out) {
    __shared__ float sh[5][256];
    const int t    = threadIdx.x;
    const int lane = t & 63;
    const int g    = t >> 6;
    const int i    = blockIdx.x * 64 + lane;      // row (coalesced across lanes)
    float s[5] = {0.0f, 0.0f, 0.0f, 0.0f, 0.0f};
    for (int jb = g * (NSLOT / 4); jb < (g + 1) * (NSLOT / 4); ++jb) {
        const size_t base = (size_t)jb * N + i;
        #pragma unroll
        for (int p = 0; p < 5; ++p) s[p] += partials[p * PL + base];
    }
    #pragma unroll
    for (int p = 0; p < 5; ++p) sh[p][t] = s[p];
    __syncthreads();
    if (g == 0) {
        float v[5];
        #pragma unroll
        for (int p = 0; p < 5; ++p)
            v[p] = sh[p][lane] + sh[p][64 + lane] + sh[p][128 + lane] + sh[p][192 + lane];
        // loss_i = (UA - WB + V*log(Zo/Zt)) / Zt^3
        float li = (v[2] - v[4] + v[1] * __logf(v[3] / v[0])) / (v[0] * v[0] * v[0]);
        #pragma unroll
        for (int m = 32; m >= 1; m >>= 1) li += __shfl_xor(li, m);
        if (lane == 0)
            atomicAdd(out, li * (1.0f / ((float)N * (float)N)));   // WEIGHT=1
    }
}

extern "C" void kernel_launch(void* const* d_in, const int* in_sizes, int n_in,
                              void* d_out, int out_size, void* d_ws, size_t ws_size,
                              hipStream_t stream) {
    (void)in_sizes; (void)n_in; (void)out_size; (void)ws_size;
    const float* mo = (const float*)d_in[0];   // model_output [8192,512] fp32
    const float* tg = (const float*)d_in[1];   // targets      [8192,768] fp32
    float* out = (float*)d_out;

    char* ws = (char*)d_ws;
    unsigned short* Xt = (unsigned short*)ws;                          // 12.58 MB
    unsigned short* Xo = (unsigned short*)(ws + (size_t)N * DT * 2);   //  8.39 MB
    float* partials    = (float*)(ws + (size_t)N * DT * 2 + (size_t)N * DO * 2);
    // partials: 5 planes * 128 * 8192 * 4 B = 20.97 MB; total ws use ~41.9 MB

    norm_kernel<<<2 * (N / 4), 256, 0, stream>>>(tg, mo, Xt, Xo, out);  // also zeroes out
    fused_kernel<<<NTILE, 256, 0, stream>>>(Xt, Xo, partials);
    reduce_kernel<<<N / 64, 256, 0, stream>>>(partials, out);
}

// Round 4
// 339.664 us; speedup vs baseline: 1.1106x; 1.1106x over previous
//
#include <hip/hip_runtime.h>

#define N    8192
#define DT   768
#define DO   512
#define BM   128
#define BN   128
#define TI   (N / BM)   // 64
#define TJ   (N / BN)   // 64
#define NTILE (TI * (TI + 1) / 2)   // 2080 upper-triangle tiles (2080 % 8 == 0)
#define NSLOT (2 * TJ)              // 128 partial slots per row
#define PL    ((size_t)NSLOT * N)   // one SoA plane: 128*8192 floats = 4 MB
#define NKT   (DT / 32)             // 24 teacher K-steps
#define NKO   (DO / 32)             // 16 student K-steps
#define NSTEP (NKT + NKO)           // 40 total K-steps

typedef __attribute__((ext_vector_type(8))) short   short8;   // 8 bf16 = 4 VGPRs
typedef __attribute__((ext_vector_type(4))) float   floatx4;

struct alignas(8) us4 { unsigned short x[4]; };

// round-to-nearest-even fp32 -> bf16
__device__ inline unsigned short f2bf(float x) {
    union { float f; unsigned int u; } v; v.f = x;
    unsigned int r = v.u + 0x7fffu + ((v.u >> 16) & 1u);
    return (unsigned short)(r >> 16);
}
__device__ inline float bf2f(unsigned short u) {
    union { unsigned int u; float f; } v; v.u = ((unsigned int)u) << 16;
    return v.f;
}

// async global->LDS, 16B per lane (global_load_lds_dwordx4)
__device__ inline void gl2lds16(const unsigned short* g, unsigned short* l) {
    __builtin_amdgcn_global_load_lds(
        (const __attribute__((address_space(1))) unsigned int*)(const void*)g,
        (__attribute__((address_space(3))) unsigned int*)(void*)l,
        16, 0, 0);
}

// stage one 128x32 A-tile and B-tile (bf16) into an LDS buffer.
// LDS destination LINEAR (global_load_lds writes base+lane*16); bank-conflict
// swizzle applied by permuting the GLOBAL source column chunk; matching XOR
// on the ds_read side (2-way residual = free). 4 VMEM instrs per thread.
template <int D>
__device__ inline void stage_tile(const unsigned short* __restrict__ Xi,
                                  const unsigned short* __restrict__ Xj,
                                  unsigned short* sAb, unsigned short* sBb,
                                  int i0, int j0, int k, int t) {
    #pragma unroll
    for (int h = 0; h < 2; ++h) {
        const int idx = t + h * 256;        // 0..511; lane-contiguous per wave
        const int r   = idx >> 2;
        const int cs  = ((idx & 3) ^ ((r >> 1) & 3)) << 3;   // swizzled col-chunk
        gl2lds16(Xi + (size_t)(i0 + r) * D + k + cs, &sAb[idx * 8]);
        gl2lds16(Xj + (size_t)(j0 + r) * D + k + cs, &sBb[idx * 8]);
    }
}

// fragment loads + 16 MFMA for one 32-wide K-step
__device__ inline void mfma_step(const unsigned short* __restrict__ sAb,
                                 const unsigned short* __restrict__ sBb,
                                 floatx4 (&acc)[4][4],
                                 int wm, int wn, int lr, int lgx) {
    short8 af[4], bf[4];
    #pragma unroll
    for (int mi = 0; mi < 4; ++mi)
        af[mi] = *(const short8*)&sAb[(wm * 64 + mi * 16 + lr) * 32 + (lgx << 3)];
    #pragma unroll
    for (int ni = 0; ni < 4; ++ni)
        bf[ni] = *(const short8*)&sBb[(wn * 64 + ni * 16 + lr) * 32 + (lgx << 3)];
    #pragma unroll
    for (int mi = 0; mi < 4; ++mi)
        #pragma unroll
        for (int ni = 0; ni < 4; ++ni)
            acc[mi][ni] = __builtin_amdgcn_mfma_f32_16x16x32_bf16(
                af[mi], bf[ni], acc[mi][ni], 0, 0, 0);
}

// ---------------- row-normalize fp32 -> bf16 (one wave per row) ----------------
__global__ void norm_kernel(const float* __restrict__ Tg,
                            const float* __restrict__ Mo,
                            unsigned short* __restrict__ Xt,
                            unsigned short* __restrict__ Xo,
                            float* __restrict__ zero_me) {
    if (blockIdx.x == 0 && threadIdx.x == 0) zero_me[0] = 0.0f;
    int bid = blockIdx.x;
    const float* X; unsigned short* Xn; int D;
    if (bid < N / 4) { X = Tg; Xn = Xt; D = DT; }
    else             { bid -= N / 4; X = Mo; Xn = Xo; D = DO; }
    const int row  = bid * 4 + (threadIdx.x >> 6);
    const int lane = threadIdx.x & 63;
    const float* xr = X + (size_t)row * D;
    float ss = 0.0f;
    for (int c = lane * 4; c < D; c += 256) {
        const floatx4 v = *(const floatx4*)(xr + c);
        ss += v[0] * v[0] + v[1] * v[1] + v[2] * v[2] + v[3] * v[3];
    }
    #pragma unroll
    for (int m = 32; m >= 1; m >>= 1) ss += __shfl_xor(ss, m);
    const float scale = 1.0f / fmaxf(sqrtf(ss), 1e-8f);
    unsigned short* outr = Xn + (size_t)row * D;
    for (int c = lane * 4; c < D; c += 256) {
        const floatx4 v = *(const floatx4*)(xr + c);
        us4 o;
        #pragma unroll
        for (int j = 0; j < 4; ++j) o.x[j] = f2bf(v[j] * scale);
        *(us4*)(outr + c) = o;
    }
}

// ---------------- fused dual-GEMM + softmax-stat tile kernel ----------------
// Symmetric-tile scheme (ti <= tj, row-sums + col-sums) as R1-R3.
// R4: triple-buffered LDS, 2-deep prefetch, COUNTED vmcnt(8) (never 0 in the
// main loop) so staging loads stay in flight across barriers (m218 lever).
// Unified step index s: 0..23 teacher (K=DT), 24..39 student (K=DO); buffer
// = s % 3. Student tiles 0-1 prefetch during the teacher epilogue.
// W = e3 parked in GLOBAL ws (bf16 pairs, coalesced [tile][pair][thread]) --
// zero register-pressure cost (R3's w3p-in-regs spilled at launch_bounds(256,3)).
__launch_bounds__(256, 3)
__global__ void fused_kernel(const unsigned short* __restrict__ Xt,
                             const unsigned short* __restrict__ Xo,
                             float* __restrict__ partials,
                             unsigned int* __restrict__ Wws) {
    __shared__ unsigned short sA[3][BM * 32];     // 3 x 8 KB
    __shared__ unsigned short sB[3][BN * 32];     // 3 x 8 KB   (total 48 KB)

    const int t    = threadIdx.x;
    const int lane = t & 63;
    const int w    = t >> 6;
    const int wm   = w >> 1, wn = w & 1;
    const int lr   = lane & 15, lg = lane >> 4;
    const int lgx  = lg ^ ((lr >> 1) & 3);        // swizzled read chunk index

    // Bijective chunked XCD swizzle (NTILE % 8 == 0 -> exact)
    const int swb = (blockIdx.x & 7) * (NTILE / 8) + (blockIdx.x >> 3);
    int rem = swb, ti = 0;
    while (rem >= TI - ti) { rem -= TI - ti; ++ti; }
    const int tj = ti + rem;
    const bool offdiag = (ti != tj);
    const int i0 = ti * BM, j0 = tj * BN;
    unsigned int* const wt = Wws + (size_t)blockIdx.x * 8192;   // this tile's W

    floatx4 acc[4][4];
    #pragma unroll
    for (int a = 0; a < 4; ++a)
        #pragma unroll
        for (int b = 0; b < 4; ++b)
            acc[a][b] = (floatx4){0.0f, 0.0f, 0.0f, 0.0f};

    // stage step s: s<NKT -> teacher k=s*32 ; else student k=(s-NKT)*32
    auto stage_any = [&](int s) {
        unsigned short* a = sA[s % 3];
        unsigned short* b = sB[s % 3];
        if (s < NKT) stage_tile<DT>(Xt, Xt, a, b, i0, j0, s * 32, t);
        else         stage_tile<DO>(Xo, Xo, a, b, i0, j0, (s - NKT) * 32, t);
    };

    // ---- prologue: 2-deep prefetch ----
    stage_any(0);
    stage_any(1);

    // ---- teacher K-loop (pipelined; kt+2 <= 25 < NSTEP so always stages) ----
    for (int kt = 0; kt < NKT; ++kt) {
        stage_any(kt + 2);
        asm volatile("s_waitcnt vmcnt(8)" ::: "memory");   // stage(kt) landed
        __builtin_amdgcn_s_barrier();
        asm volatile("" ::: "memory");
        mfma_step(sA[kt % 3], sB[kt % 3], acc, wm, wn, lr, lgx);
        asm volatile("" ::: "memory");
        __builtin_amdgcn_s_barrier();                      // protect buf reuse
        asm volatile("" ::: "memory");
    }

    // ---- teacher epilogue: Zt, V, Sum(e3*a) per row (both orientations);
    //      W=e3 -> global ws as packed bf16 pairs. Student stages 24,25 remain
    //      in flight underneath. C/D layout: col=lane&15, row=(lane>>4)*4+reg
    {
        float czt[4], cvv[4], cua[4];
        #pragma unroll
        for (int ni = 0; ni < 4; ++ni) { czt[ni] = 0.0f; cvv[ni] = 0.0f; cua[ni] = 0.0f; }
        #pragma unroll
        for (int mi = 0; mi < 4; ++mi) {
            unsigned int wpk[4][2];                        // [ni][r>>1] bf16 pairs
            #pragma unroll
            for (int r = 0; r < 4; ++r) {
                const int row = wm * 64 + mi * 16 + lg * 4 + r;
                const int gi  = i0 + row;
                float zt = 0.0f, vv = 0.0f, ua = 0.0f;
                #pragma unroll
                for (int ni = 0; ni < 4; ++ni) {
                    const int gj = j0 + wn * 64 + ni * 16 + lr;
                    const float a = acc[mi][ni][r];
                    float ea = __expf(a - 1.0f);
                    if (gi == gj) ea = 0.0f;               // diagonal -> prob 0
                    const float e3 = ea * ea * ea;
                    zt += ea; vv += e3; ua += e3 * a;
                    czt[ni] += ea; cvv[ni] += e3; cua[ni] += e3 * a;
                    if ((r & 1) == 0) wpk[ni][r >> 1]  = (unsigned int)f2bf(e3);
                    else              wpk[ni][r >> 1] |= ((unsigned int)f2bf(e3)) << 16;
                }
                #pragma unroll
                for (int m = 8; m >= 1; m >>= 1) {
                    zt += __shfl_xor(zt, m);
                    vv += __shfl_xor(vv, m);
                    ua += __shfl_xor(ua, m);
                }
                if (lr == 0) {
                    const size_t base = (size_t)(tj * 2 + wn) * N + gi;
                    partials[0 * PL + base] = zt;
                    partials[1 * PL + base] = vv;
                    partials[2 * PL + base] = ua;
                }
            }
            #pragma unroll
            for (int ni = 0; ni < 4; ++ni)
                #pragma unroll
                for (int rp = 0; rp < 2; ++rp)
                    wt[(mi * 8 + ni * 2 + rp) * 256 + t] = wpk[ni][rp];   // coalesced
        }
        if (offdiag) {
            #pragma unroll
            for (int ni = 0; ni < 4; ++ni) {
                #pragma unroll
                for (int m = 16; m <= 32; m <<= 1) {
                    czt[ni] += __shfl_xor(czt[ni], m);
                    cvv[ni] += __shfl_xor(cvv[ni], m);
                    cua[ni] += __shfl_xor(cua[ni], m);
                }
            }
            if (lg == 0) {
                #pragma unroll
                for (int ni = 0; ni < 4; ++ni) {
                    const int gj = j0 + wn * 64 + ni * 16 + lr;   // contiguous in lr
                    const size_t base = (size_t)(ti * 2 + wm) * N + gj;
                    partials[0 * PL + base] = czt[ni];
                    partials[1 * PL + base] = cvv[ni];
                    partials[2 * PL + base] = cua[ni];
                }
            }
        }
    }

    // ---- student K-loop (pipelined; steps s = 24+ko, buffer s % 3) ----
    #pragma unroll
    for (int a = 0; a < 4; ++a)
        #pragma unroll
        for (int b = 0; b < 4; ++b)
            acc[a][b] = (floatx4){0.0f, 0.0f, 0.0f, 0.0f};

    for (int ko = 0; ko < NKO; ++ko) {
        const int s = NKT + ko;
        if (ko + 2 < NKO) {
            stage_any(s + 2);
            // vmcnt(8) also drains the (older) epilogue stores at ko==0: correct,
            // one-time cost only.
            asm volatile("s_waitcnt vmcnt(8)" ::: "memory");
        } else if (ko == NKO - 2) {
            asm volatile("s_waitcnt vmcnt(4)" ::: "memory");
        } else {
            asm volatile("s_waitcnt vmcnt(0)" ::: "memory");
        }
        __builtin_amdgcn_s_barrier();
        asm volatile("" ::: "memory");
        mfma_step(sA[s % 3], sB[s % 3], acc, wm, wn, lr, lgx);
        asm volatile("" ::: "memory");
        if (ko <= NKO - 4) {                   // trailing barrier only while
            __builtin_amdgcn_s_barrier();      // a later iter still stages
            asm volatile("" ::: "memory");
        }
    }

    // ---- student epilogue: Zo, Sum(W*b) per row (both orientations) ----
    {
        unsigned int wld[32];
        #pragma unroll
        for (int pi = 0; pi < 32; ++pi)
            wld[pi] = wt[pi * 256 + t];        // coalesced, L2/L3-resident
        float czo[4], cwb[4];
        #pragma unroll
        for (int ni = 0; ni < 4; ++ni) { czo[ni] = 0.0f; cwb[ni] = 0.0f; }
        #pragma unroll
        for (int mi = 0; mi < 4; ++mi) {
            #pragma unroll
            for (int r = 0; r < 4; ++r) {
                const int row = wm * 64 + mi * 16 + lg * 4 + r;
                const int gi  = i0 + row;
                float zo = 0.0f, wb = 0.0f;
                #pragma unroll
                for (int ni = 0; ni < 4; ++ni) {
                    const int gj = j0 + wn * 64 + ni * 16 + lr;
                    const float b = acc[mi][ni][r];
                    float eb = __expf(b - 1.0f);
                    if (gi == gj) eb = 0.0f;
                    const unsigned int pw = wld[mi * 8 + ni * 2 + (r >> 1)];
                    const float wgt = bf2f((unsigned short)((r & 1) ? (pw >> 16)
                                                                    : (pw & 0xffffu)));
                    zo += eb; wb += wgt * b;   // diag: W==0 -> no contribution
                    czo[ni] += eb; cwb[ni] += wgt * b;
                }
                #pragma unroll
                for (int m = 8; m >= 1; m >>= 1) {
                    zo += __shfl_xor(zo, m);
                    wb += __shfl_xor(wb, m);
                }
                if (lr == 0) {
                    const size_t base = (size_t)(tj * 2 + wn) * N + gi;
                    partials[3 * PL + base] = zo;
                    partials[4 * PL + base] = wb;
                }
            }
        }
        if (offdiag) {
            #pragma unroll
            for (int ni = 0; ni < 4; ++ni) {
                #pragma unroll
                for (int m = 16; m <= 32; m <<= 1) {
                    czo[ni] += __shfl_xor(czo[ni], m);
                    cwb[ni] += __shfl_xor(cwb[ni], m);
                }
            }
            if (lg == 0) {
                #pragma unroll
                for (int ni = 0; ni < 4; ++ni) {
                    const int gj = j0 + wn * 64 + ni * 16 + lr;   // contiguous in lr
                    const size_t base = (size_t)(ti * 2 + wm) * N + gj;
                    partials[3 * PL + base] = czo[ni];
                    partials[4 * PL + base] = cwb[ni];
                }
            }
        }
    }
}

// ---------------- final per-row combine + scalar reduce ----------------
// 128 blocks; each block: 64 rows, 4 waves split the 128 slots (32 each),
// LDS combine, wave 0 computes per-row loss + block partial -> one atomic.
__global__ void reduce_kernel(const float* __restrict__ partials,
                              float* __restrict__ out) {
    __shared__ float sh[5][256];
    const int t    = threadIdx.x;
    const int lane = t & 63;
    const int g    = t >> 6;
    const int i    = blockIdx.x * 64 + lane;      // row (coalesced across lanes)
    float s[5] = {0.0f, 0.0f, 0.0f, 0.0f, 0.0f};
    for (int jb = g * (NSLOT / 4); jb < (g + 1) * (NSLOT / 4); ++jb) {
        const size_t base = (size_t)jb * N + i;
        #pragma unroll
        for (int p = 0; p < 5; ++p) s[p] += partials[p * PL + base];
    }
    #pragma unroll
    for (int p = 0; p < 5; ++p) sh[p][t] = s[p];
    __syncthreads();
    if (g == 0) {
        float v[5];
        #pragma unroll
        for (int p = 0; p < 5; ++p)
            v[p] = sh[p][lane] + sh[p][64 + lane] + sh[p][128 + lane] + sh[p][192 + lane];
        // loss_i = (UA - WB + V*log(Zo/Zt)) / Zt^3
        float li = (v[2] - v[4] + v[1] * __logf(v[3] / v[0])) / (v[0] * v[0] * v[0]);
        #pragma unroll
        for (int m = 32; m >= 1; m >>= 1) li += __shfl_xor(li, m);
        if (lane == 0)
            atomicAdd(out, li * (1.0f / ((float)N * (float)N)));   // WEIGHT=1
    }
}

extern "C" void kernel_launch(void* const* d_in, const int* in_sizes, int n_in,
                              void* d_out, int out_size, void* d_ws, size_t ws_size,
                              hipStream_t stream) {
    (void)in_sizes; (void)n_in; (void)out_size; (void)ws_size;
    const float* mo = (const float*)d_in[0];   // model_output [8192,512] fp32
    const float* tg = (const float*)d_in[1];   // targets      [8192,768] fp32
    float* out = (float*)d_out;

    char* ws = (char*)d_ws;
    unsigned short* Xt = (unsigned short*)ws;                          // 12.58 MB
    unsigned short* Xo = (unsigned short*)(ws + (size_t)N * DT * 2);   //  8.39 MB
    float* partials    = (float*)(ws + (size_t)N * DT * 2 + (size_t)N * DO * 2);
    // partials: 5 planes * 128 * 8192 * 4 B = 20.97 MB
    unsigned int* Wws  = (unsigned int*)((char*)partials + 5 * PL * sizeof(float));
    // Wws: 2080 tiles * 8192 u32 = 68.2 MB; total ws use ~110 MB

    norm_kernel<<<2 * (N / 4), 256, 0, stream>>>(tg, mo, Xt, Xo, out);  // also zeroes out
    fused_kernel<<<NTILE, 256, 0, stream>>>(Xt, Xo, partials, Wws);
    reduce_kernel<<<N / 64, 256, 0, stream>>>(partials, out);
}

// Round 5
// 326.078 us; speedup vs baseline: 1.1569x; 1.0417x over previous
//
#include <hip/hip_runtime.h>

#define N    8192
#define DT   768
#define DO   512
#define BM   128
#define BN   128
#define TI   (N / BM)   // 64
#define TJ   (N / BN)   // 64
#define NTILE (TI * (TI + 1) / 2)   // 2080 upper-triangle tiles (2080 % 8 == 0)
#define NSLOT (2 * TJ)              // 128 partial slots per row
#define PL    ((size_t)NSLOT * N)   // one SoA plane: 128*8192 floats = 4 MB
#define NKT   (DT / 32)             // 24 teacher K-steps
#define NKO   (DO / 32)             // 16 student K-steps
#define NSTEP (NKT + NKO)           // 40 total K-steps

typedef __attribute__((ext_vector_type(8))) short   short8;   // 8 bf16 = 4 VGPRs
typedef __attribute__((ext_vector_type(4))) float   floatx4;

struct alignas(8) us4 { unsigned short x[4]; };

// round-to-nearest-even fp32 -> bf16
__device__ inline unsigned short f2bf(float x) {
    union { float f; unsigned int u; } v; v.f = x;
    unsigned int r = v.u + 0x7fffu + ((v.u >> 16) & 1u);
    return (unsigned short)(r >> 16);
}

// async global->LDS, 16B per lane (global_load_lds_dwordx4)
__device__ inline void gl2lds16(const unsigned short* g, unsigned short* l) {
    __builtin_amdgcn_global_load_lds(
        (const __attribute__((address_space(1))) unsigned int*)(const void*)g,
        (__attribute__((address_space(3))) unsigned int*)(void*)l,
        16, 0, 0);
}

// stage one 128x32 A-tile and B-tile (bf16) into an LDS buffer.
// LDS destination LINEAR (global_load_lds writes base+lane*16); bank-conflict
// swizzle applied by permuting the GLOBAL source column chunk; matching XOR
// on the ds_read side (2-way residual = free). 4 VMEM instrs per thread.
template <int D>
__device__ inline void stage_tile(const unsigned short* __restrict__ Xi,
                                  const unsigned short* __restrict__ Xj,
                                  unsigned short* sAb, unsigned short* sBb,
                                  int i0, int j0, int k, int t) {
    #pragma unroll
    for (int h = 0; h < 2; ++h) {
        const int idx = t + h * 256;        // 0..511; lane-contiguous per wave
        const int r   = idx >> 2;
        const int cs  = ((idx & 3) ^ ((r >> 1) & 3)) << 3;   // swizzled col-chunk
        gl2lds16(Xi + (size_t)(i0 + r) * D + k + cs, &sAb[idx * 8]);
        gl2lds16(Xj + (size_t)(j0 + r) * D + k + cs, &sBb[idx * 8]);
    }
}

// fragment loads + 16 MFMA for one 32-wide K-step
__device__ inline void mfma_step(const unsigned short* __restrict__ sAb,
                                 const unsigned short* __restrict__ sBb,
                                 floatx4 (&acc)[4][4],
                                 int wm, int wn, int lr, int lgx) {
    short8 af[4], bf[4];
    #pragma unroll
    for (int mi = 0; mi < 4; ++mi)
        af[mi] = *(const short8*)&sAb[(wm * 64 + mi * 16 + lr) * 32 + (lgx << 3)];
    #pragma unroll
    for (int ni = 0; ni < 4; ++ni)
        bf[ni] = *(const short8*)&sBb[(wn * 64 + ni * 16 + lr) * 32 + (lgx << 3)];
    #pragma unroll
    for (int mi = 0; mi < 4; ++mi)
        #pragma unroll
        for (int ni = 0; ni < 4; ++ni)
            acc[mi][ni] = __builtin_amdgcn_mfma_f32_16x16x32_bf16(
                af[mi], bf[ni], acc[mi][ni], 0, 0, 0);
}

// ---------------- row-normalize fp32 -> bf16 (one wave per row) ----------------
// Loads cached in registers (single pass over X). Blocks [0,N/4): targets;
// [N/4, 2N/4): model_output. Also zeroes the output scalar.
__global__ void norm_kernel(const float* __restrict__ Tg,
                            const float* __restrict__ Mo,
                            unsigned short* __restrict__ Xt,
                            unsigned short* __restrict__ Xo,
                            float* __restrict__ zero_me) {
    if (blockIdx.x == 0 && threadIdx.x == 0) zero_me[0] = 0.0f;
    int bid = blockIdx.x;
    const float* X; unsigned short* Xn; int D;
    if (bid < N / 4) { X = Tg; Xn = Xt; D = DT; }
    else             { bid -= N / 4; X = Mo; Xn = Xo; D = DO; }
    const int row  = bid * 4 + (threadIdx.x >> 6);
    const int lane = threadIdx.x & 63;
    const int nch  = D >> 8;                       // 3 (DT) or 2 (DO)
    const float* xr = X + (size_t)row * D;
    floatx4 vc[3];
    float ss = 0.0f;
    #pragma unroll
    for (int h = 0; h < 3; ++h) {
        if (h < nch) {
            vc[h] = *(const floatx4*)(xr + lane * 4 + h * 256);
            ss += vc[h][0] * vc[h][0] + vc[h][1] * vc[h][1]
                + vc[h][2] * vc[h][2] + vc[h][3] * vc[h][3];
        }
    }
    #pragma unroll
    for (int m = 32; m >= 1; m >>= 1) ss += __shfl_xor(ss, m);
    const float scale = 1.0f / fmaxf(sqrtf(ss), 1e-8f);
    unsigned short* outr = Xn + (size_t)row * D;
    #pragma unroll
    for (int h = 0; h < 3; ++h) {
        if (h < nch) {
            us4 o;
            #pragma unroll
            for (int j = 0; j < 4; ++j) o.x[j] = f2bf(vc[h][j] * scale);
            *(us4*)(outr + lane * 4 + h * 256) = o;
        }
    }
}

// ---------------- fused dual-GEMM + softmax-stat tile kernel ----------------
// Symmetric-tile scheme (ti <= tj, row-sums + col-sums) as R1-R4.
// R5 structure:
//  * BOTH accumulators live (acc_t + acc_o = 128 VGPR) -> W is never stored
//    anywhere: ONE merged epilogue computes ea/e3/eb from registers.
//    (R3: W-in-regs spilled at 3 w/SIMD; R4: W-in-global cost 136 MB traffic.)
//  * 40 uninterrupted K-steps, 4-deep LDS ring (64 KB), 3-step lookahead,
//    ONE barrier per step: vmcnt(8) -> s_barrier -> stage(s+3) -> MFMA(s).
//    Read-safety: vmcnt(8) before the barrier => own stage(s) landed; barrier
//    publishes it for all waves. Write-safety: stage(s+3) after the barrier
//    overwrites buf[(s-1)&3], whose reads completed before this barrier
//    (each wave's MFMAs of step s-1 consumed them pre-barrier).
//  * 2 blocks/CU (launch_bounds 256,2) -- register budget for dual acc.
__launch_bounds__(256, 2)
__global__ void fused_kernel(const unsigned short* __restrict__ Xt,
                             const unsigned short* __restrict__ Xo,
                             float* __restrict__ partials) {
    __shared__ unsigned short sA[4][BM * 32];     // 4 x 8 KB
    __shared__ unsigned short sB[4][BN * 32];     // 4 x 8 KB   (total 64 KB)

    const int t    = threadIdx.x;
    const int lane = t & 63;
    const int w    = t >> 6;
    const int wm   = w >> 1, wn = w & 1;
    const int lr   = lane & 15, lg = lane >> 4;
    const int lgx  = lg ^ ((lr >> 1) & 3);        // swizzled read chunk index

    // Bijective chunked XCD swizzle (NTILE % 8 == 0 -> exact)
    const int swb = (blockIdx.x & 7) * (NTILE / 8) + (blockIdx.x >> 3);
    int rem = swb, ti = 0;
    while (rem >= TI - ti) { rem -= TI - ti; ++ti; }
    const int tj = ti + rem;
    const bool offdiag = (ti != tj);
    const int i0 = ti * BM, j0 = tj * BN;

    floatx4 acc_t[4][4], acc_o[4][4];
    #pragma unroll
    for (int a = 0; a < 4; ++a)
        #pragma unroll
        for (int b = 0; b < 4; ++b) {
            acc_t[a][b] = (floatx4){0.0f, 0.0f, 0.0f, 0.0f};
            acc_o[a][b] = (floatx4){0.0f, 0.0f, 0.0f, 0.0f};
        }

    // stage step s: s<NKT -> teacher k=s*32 ; else student k=(s-NKT)*32
    auto stage_any = [&](int s) {
        unsigned short* a = sA[s & 3];
        unsigned short* b = sB[s & 3];
        if (s < NKT) stage_tile<DT>(Xt, Xt, a, b, i0, j0, s * 32, t);
        else         stage_tile<DO>(Xo, Xo, a, b, i0, j0, (s - NKT) * 32, t);
    };

    // ---- prologue: 3-deep prefetch (12 VMEM instrs in flight) ----
    stage_any(0);
    stage_any(1);
    stage_any(2);

    // ---- teacher K-loop (s = 0..23; stage s+3 <= 26 crosses into student) ----
    for (int s = 0; s < NKT; ++s) {
        asm volatile("s_waitcnt vmcnt(8)" ::: "memory");   // own stage(s) landed
        __builtin_amdgcn_s_barrier();                      // all waves' stage(s) landed
        asm volatile("" ::: "memory");
        stage_any(s + 3);                                  // overwrites buf[(s-1)&3]
        mfma_step(sA[s & 3], sB[s & 3], acc_t, wm, wn, lr, lgx);
        asm volatile("" ::: "memory");
    }

    // ---- student K-loop (s = 24..36 full cadence) ----
    for (int s = NKT; s < NSTEP - 3; ++s) {
        asm volatile("s_waitcnt vmcnt(8)" ::: "memory");
        __builtin_amdgcn_s_barrier();
        asm volatile("" ::: "memory");
        stage_any(s + 3);
        mfma_step(sA[s & 3], sB[s & 3], acc_o, wm, wn, lr, lgx);
        asm volatile("" ::: "memory");
    }
    // ---- tail: s = 37, 38, 39 (nothing left to stage) ----
    asm volatile("s_waitcnt vmcnt(8)" ::: "memory");
    __builtin_amdgcn_s_barrier();
    asm volatile("" ::: "memory");
    mfma_step(sA[37 & 3], sB[37 & 3], acc_o, wm, wn, lr, lgx);
    asm volatile("s_waitcnt vmcnt(4)" ::: "memory");
    __builtin_amdgcn_s_barrier();
    asm volatile("" ::: "memory");
    mfma_step(sA[38 & 3], sB[38 & 3], acc_o, wm, wn, lr, lgx);
    asm volatile("s_waitcnt vmcnt(0)" ::: "memory");
    __builtin_amdgcn_s_barrier();
    asm volatile("" ::: "memory");
    mfma_step(sA[39 & 3], sB[39 & 3], acc_o, wm, wn, lr, lgx);

    // ---- single merged epilogue: all 5 stats from registers; W = e3 exact fp32.
    // C/D layout: col = lane&15, row = (lane>>4)*4 + reg
    {
        float czt[4], cvv[4], cua[4], czo[4], cwb[4];
        #pragma unroll
        for (int ni = 0; ni < 4; ++ni) {
            czt[ni] = 0.0f; cvv[ni] = 0.0f; cua[ni] = 0.0f;
            czo[ni] = 0.0f; cwb[ni] = 0.0f;
        }
        #pragma unroll
        for (int mi = 0; mi < 4; ++mi) {
            #pragma unroll
            for (int r = 0; r < 4; ++r) {
                const int row = wm * 64 + mi * 16 + lg * 4 + r;
                const int gi  = i0 + row;
                float zt = 0.0f, vv = 0.0f, ua = 0.0f, zo = 0.0f, wb = 0.0f;
                #pragma unroll
                for (int ni = 0; ni < 4; ++ni) {
                    const int gj = j0 + wn * 64 + ni * 16 + lr;
                    const float a = acc_t[mi][ni][r];
                    const float b = acc_o[mi][ni][r];
                    float ea = __expf(a - 1.0f);
                    float eb = __expf(b - 1.0f);
                    if (gi == gj) { ea = 0.0f; eb = 0.0f; }   // diagonal -> prob 0
                    const float e3 = ea * ea * ea;
                    zt += ea; vv += e3; ua += e3 * a;
                    zo += eb; wb += e3 * b;
                    czt[ni] += ea; cvv[ni] += e3; cua[ni] += e3 * a;
                    czo[ni] += eb; cwb[ni] += e3 * b;
                }
                #pragma unroll
                for (int m = 8; m >= 1; m >>= 1) {
                    zt += __shfl_xor(zt, m);
                    vv += __shfl_xor(vv, m);
                    ua += __shfl_xor(ua, m);
                    zo += __shfl_xor(zo, m);
                    wb += __shfl_xor(wb, m);
                }
                if (lr == 0) {
                    const size_t base = (size_t)(tj * 2 + wn) * N + gi;
                    partials[0 * PL + base] = zt;
                    partials[1 * PL + base] = vv;
                    partials[2 * PL + base] = ua;
                    partials[3 * PL + base] = zo;
                    partials[4 * PL + base] = wb;
                }
            }
        }
        if (offdiag) {
            #pragma unroll
            for (int ni = 0; ni < 4; ++ni) {
                #pragma unroll
                for (int m = 16; m <= 32; m <<= 1) {
                    czt[ni] += __shfl_xor(czt[ni], m);
                    cvv[ni] += __shfl_xor(cvv[ni], m);
                    cua[ni] += __shfl_xor(cua[ni], m);
                    czo[ni] += __shfl_xor(czo[ni], m);
                    cwb[ni] += __shfl_xor(cwb[ni], m);
                }
            }
            if (lg == 0) {
                #pragma unroll
                for (int ni = 0; ni < 4; ++ni) {
                    const int gj = j0 + wn * 64 + ni * 16 + lr;   // contiguous in lr
                    const size_t base = (size_t)(ti * 2 + wm) * N + gj;
                    partials[0 * PL + base] = czt[ni];
                    partials[1 * PL + base] = cvv[ni];
                    partials[2 * PL + base] = cua[ni];
                    partials[3 * PL + base] = czo[ni];
                    partials[4 * PL + base] = cwb[ni];
                }
            }
        }
    }
}

// ---------------- final per-row combine + scalar reduce ----------------
// 128 blocks; each block: 64 rows, 4 waves split the 128 slots (32 each),
// LDS combine, wave 0 computes per-row loss + block partial -> one atomic.
__global__ void reduce_kernel(const float* __restrict__ partials,
                              float* __restrict__ out) {
    __shared__ float sh[5][256];
    const int t    = threadIdx.x;
    const int lane = t & 63;
    const int g    = t >> 6;
    const int i    = blockIdx.x * 64 + lane;      // row (coalesced across lanes)
    float s[5] = {0.0f, 0.0f, 0.0f, 0.0f, 0.0f};
    for (int jb = g * (NSLOT / 4); jb < (g + 1) * (NSLOT / 4); ++jb) {
        const size_t base = (size_t)jb * N + i;
        #pragma unroll
        for (int p = 0; p < 5; ++p) s[p] += partials[p * PL + base];
    }
    #pragma unroll
    for (int p = 0; p < 5; ++p) sh[p][t] = s[p];
    __syncthreads();
    if (g == 0) {
        float v[5];
        #pragma unroll
        for (int p = 0; p < 5; ++p)
            v[p] = sh[p][lane] + sh[p][64 + lane] + sh[p][128 + lane] + sh[p][192 + lane];
        // loss_i = (UA - WB + V*log(Zo/Zt)) / Zt^3
        float li = (v[2] - v[4] + v[1] * __logf(v[3] / v[0])) / (v[0] * v[0] * v[0]);
        #pragma unroll
        for (int m = 32; m >= 1; m >>= 1) li += __shfl_xor(li, m);
        if (lane == 0)
            atomicAdd(out, li * (1.0f / ((float)N * (float)N)));   // WEIGHT=1
    }
}

extern "C" void kernel_launch(void* const* d_in, const int* in_sizes, int n_in,
                              void* d_out, int out_size, void* d_ws, size_t ws_size,
                              hipStream_t stream) {
    (void)in_sizes; (void)n_in; (void)out_size; (void)ws_size;
    const float* mo = (const float*)d_in[0];   // model_output [8192,512] fp32
    const float* tg = (const float*)d_in[1];   // targets      [8192,768] fp32
    float* out = (float*)d_out;

    char* ws = (char*)d_ws;
    unsigned short* Xt = (unsigned short*)ws;                          // 12.58 MB
    unsigned short* Xo = (unsigned short*)(ws + (size_t)N * DT * 2);   //  8.39 MB
    float* partials    = (float*)(ws + (size_t)N * DT * 2 + (size_t)N * DO * 2);
    // partials: 5 planes * 128 * 8192 * 4 B = 20.97 MB; total ws use ~41.9 MB

    norm_kernel<<<2 * (N / 4), 256, 0, stream>>>(tg, mo, Xt, Xo, out);  // also zeroes out
    fused_kernel<<<NTILE, 256, 0, stream>>>(Xt, Xo, partials);
    reduce_kernel<<<N / 64, 256, 0, stream>>>(partials, out);
}

// Round 6
// 325.023 us; speedup vs baseline: 1.1606x; 1.0032x over previous
//
#include <hip/hip_runtime.h>

#define N    8192
#define DT   768
#define DO   512
#define BM   128
#define BN   128
#define TI   (N / BM)   // 64
#define TJ   (N / BN)   // 64
#define NTILE (TI * (TI + 1) / 2)   // 2080 upper-triangle tiles (2080 % 8 == 0)
#define NSLOT (2 * TJ)              // 128 partial slots per row
#define PL    ((size_t)NSLOT * N)   // one SoA plane: 128*8192 floats = 4 MB
#define NKT   (DT / 32)             // 24 teacher K-steps
#define NKO   (DO / 32)             // 16 student K-steps

typedef __attribute__((ext_vector_type(8))) short   short8;   // 8 bf16 = 4 VGPRs
typedef __attribute__((ext_vector_type(4))) float   floatx4;

struct alignas(8) us4 { unsigned short x[4]; };

// round-to-nearest-even fp32 -> bf16
__device__ inline unsigned short f2bf(float x) {
    union { float f; unsigned int u; } v; v.f = x;
    unsigned int r = v.u + 0x7fffu + ((v.u >> 16) & 1u);
    return (unsigned short)(r >> 16);
}
__device__ inline float bf2f(unsigned short u) {
    union { unsigned int u; float f; } v; v.u = ((unsigned int)u) << 16;
    return v.f;
}

// async global->LDS, 16B per lane (global_load_lds_dwordx4)
__device__ inline void gl2lds16(const unsigned short* g, unsigned short* l) {
    __builtin_amdgcn_global_load_lds(
        (const __attribute__((address_space(1))) unsigned int*)(const void*)g,
        (__attribute__((address_space(3))) unsigned int*)(void*)l,
        16, 0, 0);
}

// stage one 128x32 A-tile and B-tile (bf16) into an LDS ring slot.
// LDS destination LINEAR (global_load_lds writes base+lane*16); bank-conflict
// swizzle applied by permuting the GLOBAL source column chunk; matching XOR
// on the ds_read side (2-way residual = free). 4 VMEM instrs per thread.
template <int D>
__device__ inline void stage_tile(const unsigned short* __restrict__ X,
                                  unsigned short* sAb, unsigned short* sBb,
                                  int i0, int j0, int k, int t) {
    #pragma unroll
    for (int h = 0; h < 2; ++h) {
        const int idx = t + h * 256;        // 0..511; lane-contiguous per wave
        const int r   = idx >> 2;
        const int cs  = ((idx & 3) ^ ((r >> 1) & 3)) << 3;   // swizzled col-chunk
        gl2lds16(X + (size_t)(i0 + r) * D + k + cs, &sAb[idx * 8]);
        gl2lds16(X + (size_t)(j0 + r) * D + k + cs, &sBb[idx * 8]);
    }
}

// fragment loads + 16 MFMA for one 32-wide K-step
__device__ inline void mfma_step(const unsigned short* __restrict__ sAb,
                                 const unsigned short* __restrict__ sBb,
                                 floatx4 (&acc)[4][4],
                                 int wm, int wn, int lr, int lgx) {
    short8 af[4], bf[4];
    #pragma unroll
    for (int mi = 0; mi < 4; ++mi)
        af[mi] = *(const short8*)&sAb[(wm * 64 + mi * 16 + lr) * 32 + (lgx << 3)];
    #pragma unroll
    for (int ni = 0; ni < 4; ++ni)
        bf[ni] = *(const short8*)&sBb[(wn * 64 + ni * 16 + lr) * 32 + (lgx << 3)];
    #pragma unroll
    for (int mi = 0; mi < 4; ++mi)
        #pragma unroll
        for (int ni = 0; ni < 4; ++ni)
            acc[mi][ni] = __builtin_amdgcn_mfma_f32_16x16x32_bf16(
                af[mi], bf[ni], acc[mi][ni], 0, 0, 0);
}

// bid -> (ti, tj) upper-triangle with bijective chunked XCD swizzle
__device__ inline void tile_coords(int bid, int& ti, int& tj) {
    const int swb = (bid & 7) * (NTILE / 8) + (bid >> 3);
    int rem = swb; int a = 0;
    while (rem >= TI - a) { rem -= TI - a; ++a; }
    ti = a; tj = a + rem;
}

// ---------------- row-normalize fp32 -> bf16 (one wave per row) ----------------
__global__ void norm_kernel(const float* __restrict__ Tg,
                            const float* __restrict__ Mo,
                            unsigned short* __restrict__ Xt,
                            unsigned short* __restrict__ Xo,
                            float* __restrict__ zero_me) {
    if (blockIdx.x == 0 && threadIdx.x == 0) zero_me[0] = 0.0f;
    int bid = blockIdx.x;
    const float* X; unsigned short* Xn; int D;
    if (bid < N / 4) { X = Tg; Xn = Xt; D = DT; }
    else             { bid -= N / 4; X = Mo; Xn = Xo; D = DO; }
    const int row  = bid * 4 + (threadIdx.x >> 6);
    const int lane = threadIdx.x & 63;
    const int nch  = D >> 8;                       // 3 (DT) or 2 (DO)
    const float* xr = X + (size_t)row * D;
    floatx4 vc[3];
    float ss = 0.0f;
    #pragma unroll
    for (int h = 0; h < 3; ++h) {
        if (h < nch) {
            vc[h] = *(const floatx4*)(xr + lane * 4 + h * 256);
            ss += vc[h][0] * vc[h][0] + vc[h][1] * vc[h][1]
                + vc[h][2] * vc[h][2] + vc[h][3] * vc[h][3];
        }
    }
    #pragma unroll
    for (int m = 32; m >= 1; m >>= 1) ss += __shfl_xor(ss, m);
    const float scale = 1.0f / fmaxf(sqrtf(ss), 1e-8f);
    unsigned short* outr = Xn + (size_t)row * D;
    #pragma unroll
    for (int h = 0; h < 3; ++h) {
        if (h < nch) {
            us4 o;
            #pragma unroll
            for (int j = 0; j < 4; ++j) o.x[j] = f2bf(vc[h][j] * scale);
            *(us4*)(outr + lane * 4 + h * 256) = o;
        }
    }
}

// ---------------- teacher kernel: GEMM + Zt/V/UA stats + W -> global ----------
// Single acc (64 f32) -> 3 blocks/CU (12 waves), ring-3 LDS (48 KB),
// lookahead-2, ONE barrier per K-step, counted vmcnt(4) (never 0 mid-loop).
// Safety: vmcnt(4) at iter s => own stage(s) landed (stage(s+1)'s 4 instrs may
// remain); barrier publishes for all waves. stage(s+2) (issued post-barrier)
// overwrites slot (s-1)%3, whose reads completed before this barrier.
__launch_bounds__(256, 3)
__global__ void fused_t_kernel(const unsigned short* __restrict__ Xt,
                               float* __restrict__ partials,
                               unsigned int* __restrict__ Wws) {
    __shared__ unsigned short sA[3][BM * 32];     // 3 x 8 KB
    __shared__ unsigned short sB[3][BN * 32];     // 3 x 8 KB   (total 48 KB)

    const int t    = threadIdx.x;
    const int lane = t & 63;
    const int w    = t >> 6;
    const int wm   = w >> 1, wn = w & 1;
    const int lr   = lane & 15, lg = lane >> 4;
    const int lgx  = lg ^ ((lr >> 1) & 3);

    int ti, tj; tile_coords(blockIdx.x, ti, tj);
    const bool offdiag = (ti != tj);
    const int i0 = ti * BM, j0 = tj * BN;
    unsigned int* const wt = Wws + (size_t)blockIdx.x * 8192;

    floatx4 acc[4][4];
    #pragma unroll
    for (int a = 0; a < 4; ++a)
        #pragma unroll
        for (int b = 0; b < 4; ++b)
            acc[a][b] = (floatx4){0.0f, 0.0f, 0.0f, 0.0f};

    stage_tile<DT>(Xt, sA[0], sB[0], i0, j0, 0, t);
    stage_tile<DT>(Xt, sA[1], sB[1], i0, j0, 32, t);

    for (int s = 0; s < NKT; ++s) {
        if (s + 1 < NKT) asm volatile("s_waitcnt vmcnt(4)" ::: "memory");
        else             asm volatile("s_waitcnt vmcnt(0)" ::: "memory");
        __builtin_amdgcn_s_barrier();
        asm volatile("" ::: "memory");
        if (s + 2 < NKT)
            stage_tile<DT>(Xt, sA[(s + 2) % 3], sB[(s + 2) % 3], i0, j0, (s + 2) * 32, t);
        mfma_step(sA[s % 3], sB[s % 3], acc, wm, wn, lr, lgx);
        asm volatile("" ::: "memory");
    }

    // ---- epilogue: Zt, V, Sum(e3*a) per row (both orientations); W packed ----
    // C/D layout: col = lane&15, row = (lane>>4)*4 + reg
    {
        float czt[4], cvv[4], cua[4];
        #pragma unroll
        for (int ni = 0; ni < 4; ++ni) { czt[ni] = 0.0f; cvv[ni] = 0.0f; cua[ni] = 0.0f; }
        #pragma unroll
        for (int mi = 0; mi < 4; ++mi) {
            unsigned int wpk[4][2];                        // [ni][r>>1] bf16 pairs
            #pragma unroll
            for (int r = 0; r < 4; ++r) {
                const int row = wm * 64 + mi * 16 + lg * 4 + r;
                const int gi  = i0 + row;
                float zt = 0.0f, vv = 0.0f, ua = 0.0f;
                #pragma unroll
                for (int ni = 0; ni < 4; ++ni) {
                    const int gj = j0 + wn * 64 + ni * 16 + lr;
                    const float a = acc[mi][ni][r];
                    float ea = __expf(a - 1.0f);
                    if (gi == gj) ea = 0.0f;               // diagonal -> prob 0
                    const float e3 = ea * ea * ea;
                    zt += ea; vv += e3; ua += e3 * a;
                    czt[ni] += ea; cvv[ni] += e3; cua[ni] += e3 * a;
                    if ((r & 1) == 0) wpk[ni][r >> 1]  = (unsigned int)f2bf(e3);
                    else              wpk[ni][r >> 1] |= ((unsigned int)f2bf(e3)) << 16;
                }
                #pragma unroll
                for (int m = 8; m >= 1; m >>= 1) {
                    zt += __shfl_xor(zt, m);
                    vv += __shfl_xor(vv, m);
                    ua += __shfl_xor(ua, m);
                }
                if (lr == 0) {
                    const size_t base = (size_t)(tj * 2 + wn) * N + gi;
                    partials[0 * PL + base] = zt;
                    partials[1 * PL + base] = vv;
                    partials[2 * PL + base] = ua;
                }
            }
            #pragma unroll
            for (int ni = 0; ni < 4; ++ni)
                #pragma unroll
                for (int rp = 0; rp < 2; ++rp)
                    wt[(mi * 8 + ni * 2 + rp) * 256 + t] = wpk[ni][rp];   // coalesced
        }
        if (offdiag) {
            #pragma unroll
            for (int ni = 0; ni < 4; ++ni) {
                #pragma unroll
                for (int m = 16; m <= 32; m <<= 1) {
                    czt[ni] += __shfl_xor(czt[ni], m);
                    cvv[ni] += __shfl_xor(cvv[ni], m);
                    cua[ni] += __shfl_xor(cua[ni], m);
                }
            }
            if (lg == 0) {
                #pragma unroll
                for (int ni = 0; ni < 4; ++ni) {
                    const int gj = j0 + wn * 64 + ni * 16 + lr;   // contiguous in lr
                    const size_t base = (size_t)(ti * 2 + wm) * N + gj;
                    partials[0 * PL + base] = czt[ni];
                    partials[1 * PL + base] = cvv[ni];
                    partials[2 * PL + base] = cua[ni];
                }
            }
        }
    }
}

// ---------------- student kernel: GEMM + Zo/WB stats (W from global) ---------
__launch_bounds__(256, 3)
__global__ void fused_o_kernel(const unsigned short* __restrict__ Xo,
                               float* __restrict__ partials,
                               const unsigned int* __restrict__ Wws) {
    __shared__ unsigned short sA[3][BM * 32];
    __shared__ unsigned short sB[3][BN * 32];

    const int t    = threadIdx.x;
    const int lane = t & 63;
    const int w    = t >> 6;
    const int wm   = w >> 1, wn = w & 1;
    const int lr   = lane & 15, lg = lane >> 4;
    const int lgx  = lg ^ ((lr >> 1) & 3);

    int ti, tj; tile_coords(blockIdx.x, ti, tj);
    const bool offdiag = (ti != tj);
    const int i0 = ti * BM, j0 = tj * BN;
    const unsigned int* const wt = Wws + (size_t)blockIdx.x * 8192;

    floatx4 acc[4][4];
    #pragma unroll
    for (int a = 0; a < 4; ++a)
        #pragma unroll
        for (int b = 0; b < 4; ++b)
            acc[a][b] = (floatx4){0.0f, 0.0f, 0.0f, 0.0f};

    stage_tile<DO>(Xo, sA[0], sB[0], i0, j0, 0, t);
    stage_tile<DO>(Xo, sA[1], sB[1], i0, j0, 32, t);

    for (int s = 0; s < NKO; ++s) {
        if (s + 1 < NKO) asm volatile("s_waitcnt vmcnt(4)" ::: "memory");
        else             asm volatile("s_waitcnt vmcnt(0)" ::: "memory");
        __builtin_amdgcn_s_barrier();
        asm volatile("" ::: "memory");
        if (s + 2 < NKO)
            stage_tile<DO>(Xo, sA[(s + 2) % 3], sB[(s + 2) % 3], i0, j0, (s + 2) * 32, t);
        mfma_step(sA[s % 3], sB[s % 3], acc, wm, wn, lr, lgx);
        asm volatile("" ::: "memory");
    }

    // ---- epilogue: Zo, Sum(W*b) per row (both orientations). W loads issued
    //      up-front; their L2/L3 latency hides under the exp/stat VALU. ----
    {
        unsigned int wld[32];
        #pragma unroll
        for (int pi = 0; pi < 32; ++pi)
            wld[pi] = wt[pi * 256 + t];        // coalesced; same-XCD L2 mostly
        float czo[4], cwb[4];
        #pragma unroll
        for (int ni = 0; ni < 4; ++ni) { czo[ni] = 0.0f; cwb[ni] = 0.0f; }
        #pragma unroll
        for (int mi = 0; mi < 4; ++mi) {
            #pragma unroll
            for (int r = 0; r < 4; ++r) {
                const int row = wm * 64 + mi * 16 + lg * 4 + r;
                const int gi  = i0 + row;
                float zo = 0.0f, wb = 0.0f;
                #pragma unroll
                for (int ni = 0; ni < 4; ++ni) {
                    const int gj = j0 + wn * 64 + ni * 16 + lr;
                    const float b = acc[mi][ni][r];
                    float eb = __expf(b - 1.0f);
                    if (gi == gj) eb = 0.0f;
                    const unsigned int pw = wld[mi * 8 + ni * 2 + (r >> 1)];
                    const float wgt = bf2f((unsigned short)((r & 1) ? (pw >> 16)
                                                                    : (pw & 0xffffu)));
                    zo += eb; wb += wgt * b;   // diag: W==0 -> no contribution
                    czo[ni] += eb; cwb[ni] += wgt * b;
                }
                #pragma unroll
                for (int m = 8; m >= 1; m >>= 1) {
                    zo += __shfl_xor(zo, m);
                    wb += __shfl_xor(wb, m);
                }
                if (lr == 0) {
                    const size_t base = (size_t)(tj * 2 + wn) * N + gi;
                    partials[3 * PL + base] = zo;
                    partials[4 * PL + base] = wb;
                }
            }
        }
        if (offdiag) {
            #pragma unroll
            for (int ni = 0; ni < 4; ++ni) {
                #pragma unroll
                for (int m = 16; m <= 32; m <<= 1) {
                    czo[ni] += __shfl_xor(czo[ni], m);
                    cwb[ni] += __shfl_xor(cwb[ni], m);
                }
            }
            if (lg == 0) {
                #pragma unroll
                for (int ni = 0; ni < 4; ++ni) {
                    const int gj = j0 + wn * 64 + ni * 16 + lr;
                    const size_t base = (size_t)(ti * 2 + wm) * N + gj;
                    partials[3 * PL + base] = czo[ni];
                    partials[4 * PL + base] = cwb[ni];
                }
            }
        }
    }
}

// ---------------- final per-row combine + scalar reduce ----------------
__global__ void reduce_kernel(const float* __restrict__ partials,
                              float* __restrict__ out) {
    __shared__ float sh[5][256];
    const int t    = threadIdx.x;
    const int lane = t & 63;
    const int g    = t >> 6;
    const int i    = blockIdx.x * 64 + lane;      // row (coalesced across lanes)
    float s[5] = {0.0f, 0.0f, 0.0f, 0.0f, 0.0f};
    for (int jb = g * (NSLOT / 4); jb < (g + 1) * (NSLOT / 4); ++jb) {
        const size_t base = (size_t)jb * N + i;
        #pragma unroll
        for (int p = 0; p < 5; ++p) s[p] += partials[p * PL + base];
    }
    #pragma unroll
    for (int p = 0; p < 5; ++p) sh[p][t] = s[p];
    __syncthreads();
    if (g == 0) {
        float v[5];
        #pragma unroll
        for (int p = 0; p < 5; ++p)
            v[p] = sh[p][lane] + sh[p][64 + lane] + sh[p][128 + lane] + sh[p][192 + lane];
        // loss_i = (UA - WB + V*log(Zo/Zt)) / Zt^3
        float li = (v[2] - v[4] + v[1] * __logf(v[3] / v[0])) / (v[0] * v[0] * v[0]);
        #pragma unroll
        for (int m = 32; m >= 1; m >>= 1) li += __shfl_xor(li, m);
        if (lane == 0)
            atomicAdd(out, li * (1.0f / ((float)N * (float)N)));   // WEIGHT=1
    }
}

extern "C" void kernel_launch(void* const* d_in, const int* in_sizes, int n_in,
                              void* d_out, int out_size, void* d_ws, size_t ws_size,
                              hipStream_t stream) {
    (void)in_sizes; (void)n_in; (void)out_size; (void)ws_size;
    const float* mo = (const float*)d_in[0];   // model_output [8192,512] fp32
    const float* tg = (const float*)d_in[1];   // targets      [8192,768] fp32
    float* out = (float*)d_out;

    char* ws = (char*)d_ws;
    unsigned short* Xt = (unsigned short*)ws;                          // 12.58 MB
    unsigned short* Xo = (unsigned short*)(ws + (size_t)N * DT * 2);   //  8.39 MB
    float* partials    = (float*)(ws + (size_t)N * DT * 2 + (size_t)N * DO * 2);
    // partials: 5 planes * 128 * 8192 * 4 B = 20.97 MB
    unsigned int* Wws  = (unsigned int*)((char*)partials + 5 * PL * sizeof(float));
    // Wws: 2080 tiles * 8192 u32 = 68.2 MB; total ws use ~110 MB

    norm_kernel<<<2 * (N / 4), 256, 0, stream>>>(tg, mo, Xt, Xo, out);  // also zeroes out
    fused_t_kernel<<<NTILE, 256, 0, stream>>>(Xt, partials, Wws);
    fused_o_kernel<<<NTILE, 256, 0, stream>>>(Xo, partials, Wws);
    reduce_kernel<<<N / 64, 256, 0, stream>>>(partials, out);
}